// Round 10
// baseline (43.654 us; speedup 1.0000x reference)
//
#include <hip/hip_runtime.h>
#include <cstdint>

#define HD __device__ __forceinline__

constexpr int B = 4, N = 8192, H = 128, W = 128, K = 8;
constexpr float BIGF = 1e10f;
constexpr int NBLK2 = 256;           // 4 batches x 64 tiles (8x8 grid of 16x16 px)
constexpr int NTHR2 = 1024;          // 16 waves/block
constexpr int BCAP = 256;            // per-subtile bucket cap (E~56, 26 sigma)

HD bool keyless(float z1, int i1, float z2, int i2) {
    return (z1 < z2) || ((z1 == z2) && (i1 < i2));
}

// branchless unrolled insert into ascending (z,idx)-sorted top-K registers.
// Caller guarantees keyless(nz,ni, zk[K-1],ik[K-1]).
HD void insert_topk(float nz, int ni, float nd,
                    float (&zk)[K], int (&ik)[K], float (&dk)[K]) {
    bool lt[K];
#pragma unroll
    for (int j = 0; j < K; ++j) lt[j] = keyless(nz, ni, zk[j], ik[j]);
#pragma unroll
    for (int j = K - 1; j >= 1; --j) {
        if (lt[j]) {
            if (lt[j - 1]) { zk[j] = zk[j - 1]; ik[j] = ik[j - 1]; dk[j] = dk[j - 1]; }
            else           { zk[j] = nz;        ik[j] = ni;        dk[j] = nd; }
        }
    }
    if (lt[0]) { zk[0] = nz; ik[0] = ni; dk[0] = nd; }
}

HD void write_out(float* __restrict__ out, int pix,
                  const float (&zk)[K], const int (&ik)[K], const float (&dk)[K]) {
    const size_t S = (size_t)B * H * W * K;
    size_t off = (size_t)pix * K;
    float fi[K], fz[K], fd[K];
#pragma unroll
    for (int j = 0; j < K; ++j) {
        bool valid = zk[j] < 0.5f * BIGF;
        fi[j] = valid ? (float)ik[j] : -1.0f;
        fz[j] = valid ? zk[j] : -1.0f;
        fd[j] = valid ? dk[j] : -1.0f;
    }
    float4* o0 = reinterpret_cast<float4*>(out + off);
    float4* o1 = reinterpret_cast<float4*>(out + S + off);
    float4* o2 = reinterpret_cast<float4*>(out + 2 * S + off);
    float4* o3 = reinterpret_cast<float4*>(out + 3 * S + off);
    o0[0] = make_float4(fi[0], fi[1], fi[2], fi[3]);
    o0[1] = make_float4(fi[4], fi[5], fi[6], fi[7]);
    o1[0] = make_float4(fz[0], fz[1], fz[2], fz[3]);
    o1[1] = make_float4(fz[4], fz[5], fz[6], fz[7]);
    o2[0] = make_float4(fi[0], fi[1], fi[2], fi[3]);
    o2[1] = make_float4(fi[4], fi[5], fi[6], fi[7]);
    o3[0] = make_float4(fd[0], fd[1], fd[2], fd[3]);
    o3[1] = make_float4(fd[4], fd[5], fd[6], fd[7]);
}

// ---------------- node 1: transform all points once into staged NDC --------
// Arithmetic bitwise-identical to rounds 8/9 (both passed at 1.9e-6):
// combined matrix C = w2v @ p2n (cols 0,1,3) + w2v col 2 built in LDS,
// then q0,q1,q3,viewz + sign-clamped divide. zn <= 0 -> sentinel x.
// Stores (xn, yn, zn, idx-bits).
__global__ __launch_bounds__(256) void transform_stage_kernel(
    const float* __restrict__ points, const float* __restrict__ w2v,
    const float* __restrict__ p2n, float4* __restrict__ staged) {
    __shared__ float lc[16];
    int tid = threadIdx.x;
    if (tid < 16) {
        int r = tid & 3, sel = tid >> 2;
        float v;
        if (sel < 3) {
            int j = (sel == 0) ? 0 : (sel == 1) ? 1 : 3;
            v = w2v[r * 4 + 0] * p2n[0 * 4 + j] + w2v[r * 4 + 1] * p2n[1 * 4 + j] +
                w2v[r * 4 + 2] * p2n[2 * 4 + j] + w2v[r * 4 + 3] * p2n[3 * 4 + j];
        } else {
            v = w2v[r * 4 + 2];      // view-z column
        }
        lc[tid] = v;
    }
    __syncthreads();

    int gid = blockIdx.x * 256 + tid;    // grid sized exactly to B*N
    float x = points[(size_t)gid * 3 + 0];
    float y = points[(size_t)gid * 3 + 1];
    float z = points[(size_t)gid * 3 + 2];
    float q0 = x * lc[0]  + y * lc[1]  + z * lc[2]  + lc[3];
    float q1 = x * lc[4]  + y * lc[5]  + z * lc[6]  + lc[7];
    float q3 = x * lc[8]  + y * lc[9]  + z * lc[10] + lc[11];
    float zn = x * lc[12] + y * lc[13] + z * lc[14] + lc[15];
    float sgn = (q3 >= 0.0f) ? 1.0f : -1.0f;
    float den = sgn * fmaxf(fabsf(q3), 1e-6f);   // always > 0
    float xn = q0 / den, yn = q1 / den;
    if (!(zn > 0.0f)) xn = 1e30f;                // sentinel: fails every bbox
    staged[gid] = make_float4(xn, yn, zn, __int_as_float(gid & (N - 1)));
}

// ---------------- node 2: tile scatter-to-LDS + select ---------------------
// One block = one (batch, 16x16-px tile). 1024 threads.
// Scan: 8 staged float4 per thread, ALL loads issued up-front (no dependent
// chain), ~12-instr bbox test each; hits (~0.2/thread) append to the 1-4
// per-8x8-subtile LDS buckets their pixel bbox touches (LDS atomicAdd).
// Select: 4 waves; wave = subtile, lane = pixel; ~56 broadcast LDS reads,
// exact d2 + top-8 by total order (z, idx) -> deterministic output.
__global__ __launch_bounds__(NTHR2, 4) void tile_select_kernel(
    const float4* __restrict__ staged, float* __restrict__ out) {
    int blk = blockIdx.x;            // 0..255
    int b = blk >> 6;                // batch
    int ti = blk & 63;
    int ty = ti >> 3, tx = ti & 7;   // 8x8 grid of 16x16-px tiles
    int tid = threadIdx.x;           // 0..1023

    __shared__ float4 list[4][BCAP]; // 16 KB
    __shared__ int lcnt[4];

    if (tid < 4) lcnt[tid] = 0;
    __syncthreads();

    const int W0 = tx * 16, H0 = ty * 16;
    const float rb = 0.0201f;        // conservative margin > RADIUS
    // tile pixel-center NDC bounds (px decreases with w, py with h)
    float pxhi = 1.0f - (2.0f * (float)W0 + 1.0f) / 128.0f;
    float pxlo = 1.0f - (2.0f * (float)(W0 + 15) + 1.0f) / 128.0f;
    float pyhi = 1.0f - (2.0f * (float)H0 + 1.0f) / 128.0f;
    float pylo = 1.0f - (2.0f * (float)(H0 + 15) + 1.0f) / 128.0f;
    float xlo = pxlo - rb, xhi = pxhi + rb;
    float ylo = pylo - rb, yhi = pyhi + rb;

    // ---- scan: load 8 staged points up-front, test, bucket hits ----
    {
        const float4* base = staged + (size_t)b * N;
        float4 e0 = base[tid];
        float4 e1 = base[tid + 1024];
        float4 e2 = base[tid + 2048];
        float4 e3 = base[tid + 3072];
        float4 e4 = base[tid + 4096];
        float4 e5 = base[tid + 5120];
        float4 e6 = base[tid + 6144];
        float4 e7 = base[tid + 7168];
        float4 ee[8] = { e0, e1, e2, e3, e4, e5, e6, e7 };
#pragma unroll
        for (int k = 0; k < 8; ++k) {
            float4 e = ee[k];
            if ((e.x >= xlo) && (e.x <= xhi) && (e.y >= ylo) && (e.y <= yhi)) {
                int wmin = (int)ceilf(((1.0f - e.x) - rb) * 64.0f - 0.5f);
                int wmax = (int)floorf(((1.0f - e.x) + rb) * 64.0f - 0.5f);
                int hmin = (int)ceilf(((1.0f - e.y) - rb) * 64.0f - 0.5f);
                int hmax = (int)floorf(((1.0f - e.y) + rb) * 64.0f - 0.5f);
                int lx0 = max(wmin - W0, 0), lx1 = min(wmax - W0, 15);
                int ly0 = max(hmin - H0, 0), ly1 = min(hmax - H0, 15);
                if (lx0 <= lx1 && ly0 <= ly1) {
                    for (int sy = ly0 >> 3; sy <= ly1 >> 3; ++sy)
                        for (int sx = lx0 >> 3; sx <= lx1 >> 3; ++sx) {
                            int bk = sy * 2 + sx;
                            int pos = atomicAdd(&lcnt[bk], 1);
                            if (pos < BCAP) list[bk][pos] = e;
                        }
                }
            }
        }
    }
    __syncthreads();

    // ---- select: 4 waves; wave = 8x8 subtile, lane = pixel ----
    if (tid < 256) {
        int s = tid >> 6, lane = tid & 63;
        int sy = s >> 1, sx = s & 1;
        int hh = H0 + sy * 8 + (lane >> 3);
        int ww = W0 + sx * 8 + (lane & 7);
        float px = 1.0f - (2.0f * (float)ww + 1.0f) / 128.0f;
        float py = 1.0f - (2.0f * (float)hh + 1.0f) / 128.0f;
        const float r2 = (float)(0.02 * 0.02);

        int cnt = lcnt[s];
        if (cnt > BCAP) cnt = BCAP;

        float zk[K]; int ik[K]; float dk[K];
#pragma unroll
        for (int j = 0; j < K; ++j) { zk[j] = BIGF; ik[j] = 0x7fffffff; dk[j] = 0.0f; }

        for (int j = 0; j < cnt; ++j) {
            float4 e = list[s][j];   // broadcast: all lanes read same address
            float dx = e.x - px, dy = e.y - py;
            float dd = __fadd_rn(__fmul_rn(dx, dx), __fmul_rn(dy, dy));
            int pi = __float_as_int(e.w);
            if ((dd <= r2) && keyless(e.z, pi, zk[K - 1], ik[K - 1]))
                insert_topk(e.z, pi, dd, zk, ik, dk);
        }
        int pix = (b << 14) + (hh << 7) + ww;
        write_out(out, pix, zk, ik, dk);
    }
}

// ---------------- fallback: brute force (no workspace needed) ----------------
HD void transform_point_full(const float* __restrict__ w2v, const float* __restrict__ p2n,
                             float x, float y, float z,
                             float& xn, float& yn, float& zn) {
    float pv[4];
#pragma unroll
    for (int j = 0; j < 4; ++j)
        pv[j] = x * w2v[0 * 4 + j] + y * w2v[1 * 4 + j] +
                z * w2v[2 * 4 + j] + 1.0f * w2v[3 * 4 + j];
    float viewz = pv[2];
    float q0 = pv[0] * p2n[0] + pv[1] * p2n[4] + pv[2] * p2n[8]  + pv[3] * p2n[12];
    float q1 = pv[0] * p2n[1] + pv[1] * p2n[5] + pv[2] * p2n[9]  + pv[3] * p2n[13];
    float q3 = pv[0] * p2n[3] + pv[1] * p2n[7] + pv[2] * p2n[11] + pv[3] * p2n[15];
    float sgn = (q3 >= 0.0f) ? 1.0f : -1.0f;
    float den = sgn * fmaxf(fabsf(q3), 1e-6f);
    xn = q0 / den; yn = q1 / den; zn = viewz;
}

__global__ __launch_bounds__(256) void brute_kernel(
    const float* __restrict__ points, const float* __restrict__ w2v,
    const float* __restrict__ p2n, float* __restrict__ out) {
    int gid = blockIdx.x * 256 + threadIdx.x;   // 0..B*H*W-1
    int b = gid >> 14;
    float px = 1.0f - (2.0f * (float)(gid & 127) + 1.0f) / 128.0f;
    float py = 1.0f - (2.0f * (float)((gid >> 7) & 127) + 1.0f) / 128.0f;
    const float r2 = (float)(0.02 * 0.02);

    __shared__ float4 sh[256];

    float zk[K]; int ik[K]; float dk[K];
#pragma unroll
    for (int j = 0; j < K; ++j) { zk[j] = BIGF; ik[j] = 0x7fffffff; dk[j] = 0.0f; }

    for (int c = 0; c < N; c += 256) {
        __syncthreads();
        int n = c + threadIdx.x;
        float x = points[((size_t)b * N + n) * 3 + 0];
        float y = points[((size_t)b * N + n) * 3 + 1];
        float z = points[((size_t)b * N + n) * 3 + 2];
        float xn, yn, zn;
        transform_point_full(w2v, p2n, x, y, z, xn, yn, zn);
        sh[threadIdx.x] = make_float4(xn, yn, zn, __int_as_float(n));
        __syncthreads();
        for (int e = 0; e < 256; ++e) {
            float4 pe = sh[e];
            float dx = pe.x - px, dy = pe.y - py;
            float d2 = __fadd_rn(__fmul_rn(dx, dx), __fmul_rn(dy, dy));
            int pi = __float_as_int(pe.w);
            if ((d2 <= r2) && (pe.z > 0.0f) && keyless(pe.z, pi, zk[K - 1], ik[K - 1]))
                insert_topk(pe.z, pi, d2, zk, ik, dk);
        }
    }
    write_out(out, gid, zk, ik, dk);
}

extern "C" void kernel_launch(void* const* d_in, const int* in_sizes, int n_in,
                              void* d_out, int out_size, void* d_ws, size_t ws_size,
                              hipStream_t stream) {
    const float* points = (const float*)d_in[0];
    const float* w2v    = (const float*)d_in[1];
    const float* p2n    = (const float*)d_in[2];
    float* out = (float*)d_out;

    const size_t need = (size_t)B * N * sizeof(float4);   // 512 KB staged
    if (ws_size >= need) {
        float4* staged = (float4*)d_ws;
        transform_stage_kernel<<<(B * N) / 256, 256, 0, stream>>>(points, w2v, p2n, staged);
        tile_select_kernel<<<NBLK2, NTHR2, 0, stream>>>(staged, out);
    } else {
        brute_kernel<<<(B * H * W) / 256, 256, 0, stream>>>(points, w2v, p2n, out);
    }
}

// Round 11
// 29.093 us; speedup vs baseline: 1.5005x; 1.5005x over previous
//
#include <hip/hip_runtime.h>
#include <cstdint>

#define HD __device__ __forceinline__

constexpr int B = 4, N = 8192, H = 128, W = 128, K = 8;
constexpr float BIGF = 1e10f;
constexpr int TOTPIX = B * H * W;   // 65536
constexpr int CAPP = 32;            // per-pixel list capacity (E[hits]~2.6)

HD bool keyless(float z1, int i1, float z2, int i2) {
    return (z1 < z2) || ((z1 == z2) && (i1 < i2));
}

// branchless unrolled insert into ascending (z,idx)-sorted top-K registers.
// Caller guarantees keyless(nz,ni, zk[K-1],ik[K-1]).
HD void insert_topk(float nz, int ni, float nd,
                    float (&zk)[K], int (&ik)[K], float (&dk)[K]) {
    bool lt[K];
#pragma unroll
    for (int j = 0; j < K; ++j) lt[j] = keyless(nz, ni, zk[j], ik[j]);
#pragma unroll
    for (int j = K - 1; j >= 1; --j) {
        if (lt[j]) {
            if (lt[j - 1]) { zk[j] = zk[j - 1]; ik[j] = ik[j - 1]; dk[j] = dk[j - 1]; }
            else           { zk[j] = nz;        ik[j] = ni;        dk[j] = nd; }
        }
    }
    if (lt[0]) { zk[0] = nz; ik[0] = ni; dk[0] = nd; }
}

HD void write_out(float* __restrict__ out, int pix,
                  const float (&zk)[K], const int (&ik)[K], const float (&dk)[K]) {
    const size_t S = (size_t)TOTPIX * K;
    size_t off = (size_t)pix * K;
    float fi[K], fz[K], fd[K];
#pragma unroll
    for (int j = 0; j < K; ++j) {
        bool valid = zk[j] < 0.5f * BIGF;
        fi[j] = valid ? (float)ik[j] : -1.0f;
        fz[j] = valid ? zk[j] : -1.0f;
        fd[j] = valid ? dk[j] : -1.0f;
    }
    float4* o0 = reinterpret_cast<float4*>(out + off);
    float4* o1 = reinterpret_cast<float4*>(out + S + off);
    float4* o2 = reinterpret_cast<float4*>(out + 2 * S + off);
    float4* o3 = reinterpret_cast<float4*>(out + 3 * S + off);
    o0[0] = make_float4(fi[0], fi[1], fi[2], fi[3]);
    o0[1] = make_float4(fi[4], fi[5], fi[6], fi[7]);
    o1[0] = make_float4(fz[0], fz[1], fz[2], fz[3]);
    o1[1] = make_float4(fz[4], fz[5], fz[6], fz[7]);
    o2[0] = make_float4(fi[0], fi[1], fi[2], fi[3]);
    o2[1] = make_float4(fi[4], fi[5], fi[6], fi[7]);
    o3[0] = make_float4(fd[0], fd[1], fd[2], fd[3]);
    o3[1] = make_float4(fd[4], fd[5], fd[6], fd[7]);
}

// ---------------- node 1: zero counters + transform all points -------------
// 32768 threads. First 16384 zero the 256 KB counter array (int4 each, in
// parallel with everything else); every thread transforms one point with the
// combined matrix C = w2v @ p2n (cols 0,1,3) + w2v col 2 (bitwise-identical
// to rounds 8-10, all passed at 1.9e-6). zn <= 0 -> sentinel xn that fails
// the bin quick-reject.
__global__ __launch_bounds__(256) void stage_zero_kernel(
    const float* __restrict__ points, const float* __restrict__ w2v,
    const float* __restrict__ p2n, float4* __restrict__ staged,
    int4* __restrict__ cnt4) {
    __shared__ float lc[16];
    int tid = threadIdx.x;
    if (tid < 16) {
        int r = tid & 3, sel = tid >> 2;
        float v;
        if (sel < 3) {
            int j = (sel == 0) ? 0 : (sel == 1) ? 1 : 3;
            v = w2v[r * 4 + 0] * p2n[0 * 4 + j] + w2v[r * 4 + 1] * p2n[1 * 4 + j] +
                w2v[r * 4 + 2] * p2n[2 * 4 + j] + w2v[r * 4 + 3] * p2n[3 * 4 + j];
        } else {
            v = w2v[r * 4 + 2];      // view-z column
        }
        lc[tid] = v;
    }
    __syncthreads();

    int gid = blockIdx.x * 256 + tid;    // 0..B*N-1 (grid sized exactly)
    if (gid < TOTPIX / 4) cnt4[gid] = make_int4(0, 0, 0, 0);

    float x = points[(size_t)gid * 3 + 0];
    float y = points[(size_t)gid * 3 + 1];
    float z = points[(size_t)gid * 3 + 2];
    float q0 = x * lc[0]  + y * lc[1]  + z * lc[2]  + lc[3];
    float q1 = x * lc[4]  + y * lc[5]  + z * lc[6]  + lc[7];
    float q3 = x * lc[8]  + y * lc[9]  + z * lc[10] + lc[11];
    float zn = x * lc[12] + y * lc[13] + z * lc[14] + lc[15];
    float sgn = (q3 >= 0.0f) ? 1.0f : -1.0f;
    float den = sgn * fmaxf(fabsf(q3), 1e-6f);   // always > 0
    float xn = q0 / den, yn = q1 / den;
    if (!(zn > 0.0f)) xn = 1e30f;                // sentinel: fails quick-reject
    staged[gid] = make_float4(xn, yn, zn, __int_as_float(gid & (N - 1)));
}

// ---------------- node 2: exact per-pixel binning from staged --------------
// 32768 threads, one per point: quick-reject (|xn| or |yn| beyond any pixel
// center + RADIUS margin: 127/128 + 0.0201 = 1.0123), tiny pixel bbox
// (~2.6 avg, <= 9 cells), exact d2 test per cell, true hits (z, d2, idx) go
// to per-pixel lists laid out [slot][pixel] (coalesced select reads).
// List order is nondeterministic; selection is by total order (z, idx).
__global__ __launch_bounds__(256) void bin_kernel(
    const float4* __restrict__ staged, int* __restrict__ cnt,
    float4* __restrict__ entries) {
    int gid = blockIdx.x * 256 + threadIdx.x;   // 0..B*N-1
    float4 e = staged[gid];
    if (fabsf(e.x) > 1.013f || fabsf(e.y) > 1.013f) return;  // also kills sentinel
    int b = gid >> 13;           // N = 8192

    const float rb = 0.0201f;    // conservative bbox; exact d2 filter below
    const float r2 = (float)(0.02 * 0.02);
    int wmin = (int)ceilf(((1.0f - e.x) - rb) * 64.0f - 0.5f);
    int wmax = (int)floorf(((1.0f - e.x) + rb) * 64.0f - 0.5f);
    int hmin = (int)ceilf(((1.0f - e.y) - rb) * 64.0f - 0.5f);
    int hmax = (int)floorf(((1.0f - e.y) + rb) * 64.0f - 0.5f);
    wmin = max(wmin, 0); wmax = min(wmax, W - 1);
    hmin = max(hmin, 0); hmax = min(hmax, H - 1);

    for (int h = hmin; h <= hmax; ++h) {
        float py = 1.0f - (2.0f * (float)h + 1.0f) / 128.0f;
        float dy = e.y - py;
        float dy2 = __fmul_rn(dy, dy);
        for (int w = wmin; w <= wmax; ++w) {
            float px = 1.0f - (2.0f * (float)w + 1.0f) / 128.0f;
            float dx = e.x - px;
            float d2 = __fadd_rn(__fmul_rn(dx, dx), dy2);
            if (d2 <= r2) {
                int pix = (b << 14) + (h << 7) + w;
                int pos = atomicAdd(&cnt[pix], 1);
                if (pos < CAPP)
                    entries[(size_t)pos * TOTPIX + pix] =
                        make_float4(e.z, d2, e.w, 0.0f);
            }
        }
    }
}

// ---------------- node 3: per-pixel top-8 selection (R4-proven) ------------
__global__ __launch_bounds__(256) void select_kernel(
    const int* __restrict__ cnt, const float4* __restrict__ entries,
    float* __restrict__ out) {
    int pix = blockIdx.x * 256 + threadIdx.x;   // 0..TOTPIX-1
    int c = cnt[pix];
    if (c > CAPP) c = CAPP;

    float zk[K]; int ik[K]; float dk[K];
#pragma unroll
    for (int j = 0; j < K; ++j) { zk[j] = BIGF; ik[j] = 0x7fffffff; dk[j] = 0.0f; }

    for (int j = 0; j < c; ++j) {
        float4 e = entries[(size_t)j * TOTPIX + pix];   // coalesced across lanes
        int pi = __float_as_int(e.z);
        if (keyless(e.x, pi, zk[K - 1], ik[K - 1]))
            insert_topk(e.x, pi, e.y, zk, ik, dk);
    }
    write_out(out, pix, zk, ik, dk);
}

// ---------------- fallback: brute force (no workspace needed) ----------------
HD void transform_point_full(const float* __restrict__ w2v, const float* __restrict__ p2n,
                             float x, float y, float z,
                             float& xn, float& yn, float& zn) {
    float pv[4];
#pragma unroll
    for (int j = 0; j < 4; ++j)
        pv[j] = x * w2v[0 * 4 + j] + y * w2v[1 * 4 + j] +
                z * w2v[2 * 4 + j] + 1.0f * w2v[3 * 4 + j];
    float viewz = pv[2];
    float q0 = pv[0] * p2n[0] + pv[1] * p2n[4] + pv[2] * p2n[8]  + pv[3] * p2n[12];
    float q1 = pv[0] * p2n[1] + pv[1] * p2n[5] + pv[2] * p2n[9]  + pv[3] * p2n[13];
    float q3 = pv[0] * p2n[3] + pv[1] * p2n[7] + pv[2] * p2n[11] + pv[3] * p2n[15];
    float sgn = (q3 >= 0.0f) ? 1.0f : -1.0f;
    float den = sgn * fmaxf(fabsf(q3), 1e-6f);
    xn = q0 / den; yn = q1 / den; zn = viewz;
}

__global__ __launch_bounds__(256) void brute_kernel(
    const float* __restrict__ points, const float* __restrict__ w2v,
    const float* __restrict__ p2n, float* __restrict__ out) {
    int gid = blockIdx.x * 256 + threadIdx.x;   // 0..B*H*W-1
    int b = gid >> 14;
    float px = 1.0f - (2.0f * (float)(gid & 127) + 1.0f) / 128.0f;
    float py = 1.0f - (2.0f * (float)((gid >> 7) & 127) + 1.0f) / 128.0f;
    const float r2 = (float)(0.02 * 0.02);

    __shared__ float4 sh[256];

    float zk[K]; int ik[K]; float dk[K];
#pragma unroll
    for (int j = 0; j < K; ++j) { zk[j] = BIGF; ik[j] = 0x7fffffff; dk[j] = 0.0f; }

    for (int c = 0; c < N; c += 256) {
        __syncthreads();
        int n = c + threadIdx.x;
        float x = points[((size_t)b * N + n) * 3 + 0];
        float y = points[((size_t)b * N + n) * 3 + 1];
        float z = points[((size_t)b * N + n) * 3 + 2];
        float xn, yn, zn;
        transform_point_full(w2v, p2n, x, y, z, xn, yn, zn);
        sh[threadIdx.x] = make_float4(xn, yn, zn, __int_as_float(n));
        __syncthreads();
        for (int e = 0; e < 256; ++e) {
            float4 pe = sh[e];
            float dx = pe.x - px, dy = pe.y - py;
            float d2 = __fadd_rn(__fmul_rn(dx, dx), __fmul_rn(dy, dy));
            int pi = __float_as_int(pe.w);
            if ((d2 <= r2) && (pe.z > 0.0f) && keyless(pe.z, pi, zk[K - 1], ik[K - 1]))
                insert_topk(pe.z, pi, d2, zk, ik, dk);
        }
    }
    write_out(out, gid, zk, ik, dk);
}

extern "C" void kernel_launch(void* const* d_in, const int* in_sizes, int n_in,
                              void* d_out, int out_size, void* d_ws, size_t ws_size,
                              hipStream_t stream) {
    const float* points = (const float*)d_in[0];
    const float* w2v    = (const float*)d_in[1];
    const float* p2n    = (const float*)d_in[2];
    float* out = (float*)d_out;

    // ws layout: cnt [0, 256KB) | staged [256KB, 768KB) | entries [1MB, 33MB)
    const size_t staged_off = 256 << 10;
    const size_t ent_off    = 1 << 20;
    const size_t need = ent_off + (size_t)CAPP * TOTPIX * sizeof(float4); // ~33MB

    if (ws_size >= need) {
        int* cnt        = (int*)d_ws;
        float4* staged  = (float4*)((char*)d_ws + staged_off);
        float4* entries = (float4*)((char*)d_ws + ent_off);
        stage_zero_kernel<<<(B * N) / 256, 256, 0, stream>>>(points, w2v, p2n,
                                                             staged, (int4*)cnt);
        bin_kernel<<<(B * N) / 256, 256, 0, stream>>>(staged, cnt, entries);
        select_kernel<<<TOTPIX / 256, 256, 0, stream>>>(cnt, entries, out);
    } else {
        brute_kernel<<<(B * H * W) / 256, 256, 0, stream>>>(points, w2v, p2n, out);
    }
}